// Round 3
// 2142.763 us; speedup vs baseline: 1.1252x; 1.1252x over previous
//
#include <hip/hip_runtime.h>

// ---------------------------------------------------------------------------
// CEBlock: LN1 -> QKV -> attention (materialized) -> proj+res -> prune(sort)
//          -> gather -> LN2 -> MLP(GELU exact) + res
// Precision split:
//   * sort path (a_ps/a_s column means) : fp64 accumulation, DETERMINISTIC
//     (no atomics; fixed-order reduction; sort on doubles)
//   * everything else                   : bf16 MFMA, fp32 accumulate
// R1: V stored transposed (B,H,64,576) -> barrier-free PV from global/L2;
//     softmax normalize fused into nontemporal attn-out store; cvt_pk bf16.
// R2: sort path determinism. atomicAdd fp32 accumulation caused run-to-run
//     rank flips at the keep/remove boundary (absmax 128 vs 176 across runs
//     with identical sort code). Now: per-(ig,h,b) fp64 partials -> fixed-
//     order fp64 reduce -> fp64 bitonic sort. Same result every run.
// ---------------------------------------------------------------------------

typedef unsigned short u16;
typedef unsigned int   u32;
typedef __attribute__((ext_vector_type(8))) short  s16x8;
typedef __attribute__((ext_vector_type(8))) __bf16 bf16x8;
typedef __attribute__((ext_vector_type(4))) float  f32x4;

#define BATCH 32
#define NTOK  576
#define CDIM  768
#define NH    12
#define HD    64
#define NKEEP 180
#define NREM  76
#define NTOK2 424
#define HID   3072

// output offsets (in floats)
#define O0 0
#define O1 10420224
#define O2 10422272
#define O3 10428032
#define O4 10433792
#define O5 10436224
#define O6 10438656

// workspace offsets (bytes)
#define WS_QKV 0u            /* 84,934,656  (later reused as MLP mid) */
#define WS_XA  84934656u     /* 28,311,552  (pre-attn: fp64 sort partials) */
#define WS_X1  113246208u    /* 56,623,104 */
#define WS_H2  169869312u    /* 20,840,448  (pre-gather: fp64 attnt) */
#define WS_WQ  190709760u
#define WS_WP  194248704u
#define WS_W1  195428352u
#define WS_W2  200146944u
#define WS_AT  204865536u
#define WS_TOP 204931072u

#define QKVSZ 14155776u      /* BATCH*NH*NTOK*HD elements */

__device__ __forceinline__ u16 f2bf(float f) {
  u32 x = __float_as_uint(f);
  x += 0x7fffu + ((x >> 16) & 1u);     // round-to-nearest-even
  return (u16)(x >> 16);
}

__device__ __forceinline__ f32x4 mfma16(s16x8 a, s16x8 b, f32x4 c) {
  return __builtin_amdgcn_mfma_f32_16x16x32_bf16(
      __builtin_bit_cast(bf16x8, a), __builtin_bit_cast(bf16x8, b), c, 0, 0, 0);
}

__device__ __forceinline__ float block_sum256(float v, float* sc) {
#pragma unroll
  for (int o = 32; o; o >>= 1) v += __shfl_down(v, o);
  int w = threadIdx.x >> 6;
  if ((threadIdx.x & 63) == 0) sc[w] = v;
  __syncthreads();
  float r = (sc[0] + sc[1]) + (sc[2] + sc[3]);
  __syncthreads();
  return r;
}

// ---------------- fp32 -> bf16 weight conversion ---------------------------
__global__ __launch_bounds__(256) void cvt_bf16(const float* __restrict__ in,
                                                u16* __restrict__ out, int n4) {
  int i = blockIdx.x * 256 + threadIdx.x;
  if (i < n4) {
    float4 v = ((const float4*)in)[i];
    union { u16 u[4]; uint2 q; } r;
    r.u[0] = f2bf(v.x); r.u[1] = f2bf(v.y); r.u[2] = f2bf(v.z); r.u[3] = f2bf(v.w);
    ((uint2*)out)[i] = r.q;
  }
}

// ---------------- LN1: x -> h (bf16 + fp32) --------------------------------
__global__ __launch_bounds__(256)
void ln1_kernel(const float* __restrict__ x, const float* __restrict__ w,
                const float* __restrict__ bb, u16* __restrict__ hb,
                float* __restrict__ hf) {
  __shared__ float sc[4];
  size_t row = blockIdx.x;
  const float* xr = x + row * CDIM;
  int t = threadIdx.x;
  float v0 = xr[t], v1 = xr[t + 256], v2 = xr[t + 512];
  float mean = block_sum256(v0 + v1 + v2, sc) / 768.0f;
  float d0 = v0 - mean, d1 = v1 - mean, d2 = v2 - mean;
  float var = block_sum256(d0 * d0 + d1 * d1 + d2 * d2, sc) / 768.0f;
  float rs = 1.0f / sqrtf(var + 1e-5f);
  float o0 = d0 * rs * w[t]       + bb[t];
  float o1 = d1 * rs * w[t + 256] + bb[t + 256];
  float o2 = d2 * rs * w[t + 512] + bb[t + 512];
  u16* hr = hb + row * CDIM;
  float* fr = hf + row * CDIM;
  hr[t] = f2bf(o0); hr[t + 256] = f2bf(o1); hr[t + 512] = f2bf(o2);
  fr[t] = o0; fr[t + 256] = o1; fr[t + 512] = o2;
}

// ---------------- bf16 MFMA GEMM: C = A(MxK) * B(NxK)^T + epilogue ---------
// MODE 0: outf = acc + bias + res (fp32)       (proj, fc2; res may alias outf)
// MODE 1: outh = bf16(gelu(acc + bias))        (fc1)
// MODE 2: qkv scatter; q,k -> (B,H,N,D); v -> (B,H,D,N) transposed   (qkv)
template <int MODE>
__global__ __launch_bounds__(256)
void gemm_bt(const u16* __restrict__ A, const u16* __restrict__ Bw,
             const float* __restrict__ bias, const float* res, float* outf,
             u16* outh, int M, int N, int K) {
  __shared__ __align__(16) u16 As[64][32];
  __shared__ __align__(16) u16 Bs[64][32];
  int t = threadIdx.x;
  int wave = t >> 6, lane = t & 63, quad = lane >> 4, l16 = lane & 15;
  int wm = (wave >> 1) * 32, wn = (wave & 1) * 32;
  int m0 = blockIdx.y * 64, n0 = blockIdx.x * 64;
  int lrow = t >> 2, lk = (t & 3) * 8;
  const u16* Ap = A + (size_t)(m0 + lrow) * K + lk;
  const u16* Bp = Bw + (size_t)(n0 + lrow) * K + lk;
  f32x4 acc[2][2] = {};
  for (int k0 = 0; k0 < K; k0 += 32) {
    *(uint4*)&As[lrow][lk] = *(const uint4*)(Ap + k0);
    *(uint4*)&Bs[lrow][lk] = *(const uint4*)(Bp + k0);
    __syncthreads();
    s16x8 af0 = *(const s16x8*)&As[wm + l16][quad * 8];
    s16x8 af1 = *(const s16x8*)&As[wm + 16 + l16][quad * 8];
    s16x8 bf0 = *(const s16x8*)&Bs[wn + l16][quad * 8];
    s16x8 bf1 = *(const s16x8*)&Bs[wn + 16 + l16][quad * 8];
    acc[0][0] = mfma16(af0, bf0, acc[0][0]);
    acc[0][1] = mfma16(af0, bf1, acc[0][1]);
    acc[1][0] = mfma16(af1, bf0, acc[1][0]);
    acc[1][1] = mfma16(af1, bf1, acc[1][1]);
    __syncthreads();
  }
#pragma unroll
  for (int mi = 0; mi < 2; ++mi)
#pragma unroll
    for (int ni = 0; ni < 2; ++ni) {
      int col = n0 + wn + ni * 16 + l16;
      float bv = bias[col];
      if (MODE == 2) {
        int three = col / 768;
        int rem = col - three * 768;
        int hh = rem >> 6, dd = rem & 63;
        int row0 = m0 + wm + mi * 16 + quad * 4;
        int bbx = row0 / 576, tok = row0 - bbx * 576;
        union { u16 u[4]; uint2 q; } pk;
#pragma unroll
        for (int r = 0; r < 4; ++r) pk.u[r] = f2bf(acc[mi][ni][r] + bv);
        if (three == 2) {
          // V transposed: (B,H,D,N); 4 consecutive toks -> one uint2 store
          *(uint2*)&outh[2u * QKVSZ +
                         ((size_t)(bbx * NH + hh) * HD + dd) * NTOK + tok] = pk.q;
        } else {
          u16* o = outh + (size_t)three * QKVSZ +
                   ((size_t)(bbx * NH + hh) * NTOK + tok) * HD + dd;
#pragma unroll
          for (int r = 0; r < 4; ++r) o[(size_t)r * HD] = pk.u[r];
        }
      } else {
#pragma unroll
        for (int r = 0; r < 4; ++r) {
          int rowi = m0 + wm + mi * 16 + quad * 4 + r;
          float v = acc[mi][ni][r] + bv;
          if (MODE == 0) {
            size_t o = (size_t)rowi * N + col;
            outf[o] = v + res[o];
          } else {
            float g = 0.5f * v * (1.0f + erff(v * 0.70710678118654752f));
            outh[(size_t)rowi * N + col] = f2bf(g);
          }
        }
      }
    }
}

// ---------------- fp32 GEMM (precision path): C = A(MxK)*W(NxK)^T + bias ---
// MODE 0: k scatter  (m0 = by*64, out (B,H,576,64))
// MODE 1: q scatter  (m0 = by*576, rows 0..63 of batch, out (B,H,64,64))
template <int MODE>
__global__ __launch_bounds__(256)
void gemm_f32(const float* __restrict__ A, const float* __restrict__ W,
              const float* __restrict__ bias, float* __restrict__ out,
              int M, int N, int K) {
  __shared__ float As[16][64];
  __shared__ float Bs[16][64];
  int t = threadIdx.x;
  int tx = t & 15, ty = t >> 4;
  int n0 = blockIdx.x * 64;
  int m0 = (MODE == 1) ? blockIdx.y * 576 : blockIdx.y * 64;
  int lr = t >> 2, lc = (t & 3) * 4;
  float acc[4][4] = {};
  for (int k0 = 0; k0 < K; k0 += 16) {
    float4 av = *(const float4*)(A + (size_t)(m0 + lr) * K + k0 + lc);
    float4 bv = *(const float4*)(W + (size_t)(n0 + lr) * K + k0 + lc);
    __syncthreads();
    As[lc + 0][lr] = av.x; As[lc + 1][lr] = av.y;
    As[lc + 2][lr] = av.z; As[lc + 3][lr] = av.w;
    Bs[lc + 0][lr] = bv.x; Bs[lc + 1][lr] = bv.y;
    Bs[lc + 2][lr] = bv.z; Bs[lc + 3][lr] = bv.w;
    __syncthreads();
#pragma unroll
    for (int kk = 0; kk < 16; ++kk) {
      float4 a4 = *(const float4*)&As[kk][ty * 4];
      float4 b4 = *(const float4*)&Bs[kk][tx * 4];
      acc[0][0] = fmaf(a4.x, b4.x, acc[0][0]);
      acc[0][1] = fmaf(a4.x, b4.y, acc[0][1]);
      acc[0][2] = fmaf(a4.x, b4.z, acc[0][2]);
      acc[0][3] = fmaf(a4.x, b4.w, acc[0][3]);
      acc[1][0] = fmaf(a4.y, b4.x, acc[1][0]);
      acc[1][1] = fmaf(a4.y, b4.y, acc[1][1]);
      acc[1][2] = fmaf(a4.y, b4.z, acc[1][2]);
      acc[1][3] = fmaf(a4.y, b4.w, acc[1][3]);
      acc[2][0] = fmaf(a4.z, b4.x, acc[2][0]);
      acc[2][1] = fmaf(a4.z, b4.y, acc[2][1]);
      acc[2][2] = fmaf(a4.z, b4.z, acc[2][2]);
      acc[2][3] = fmaf(a4.z, b4.w, acc[2][3]);
      acc[3][0] = fmaf(a4.w, b4.x, acc[3][0]);
      acc[3][1] = fmaf(a4.w, b4.y, acc[3][1]);
      acc[3][2] = fmaf(a4.w, b4.z, acc[3][2]);
      acc[3][3] = fmaf(a4.w, b4.w, acc[3][3]);
    }
  }
#pragma unroll
  for (int i = 0; i < 4; ++i) {
    int rowl = ty * 4 + i;
#pragma unroll
    for (int j = 0; j < 4; ++j) {
      int col = n0 + tx * 4 + j;
      float v = acc[i][j] + bias[col];
      int hh = col >> 6, dd = col & 63;
      if (MODE == 0) {
        int rowg = m0 + rowl;
        int bbx = rowg / 576, tok = rowg - bbx * 576;
        out[((size_t)(bbx * NH + hh) * NTOK + tok) * HD + dd] = v;
      } else {
        out[((size_t)(blockIdx.y * NH + hh) * 64 + rowl) * HD + dd] = v;
      }
    }
  }
}

// ---------------- precise fp64 scores for the sort path --------------------
// grid (4 igroups of 16 template queries, 12 heads, 32 batches)
// Deterministic: no atomics. fp64 dot (fp32 products exact in double),
// fp64 max/z, per-(ig,h,b) fp64 partial column sums -> scratch.
__global__ __launch_bounds__(256)
void precise_scores(const float* __restrict__ qf, const float* __restrict__ kf,
                    double* __restrict__ part) {
  int ig = blockIdx.x, h = blockIdx.y, b = blockIdx.z;
  __shared__ float Sp[16][576];      // holds exp(s-m) as float
  __shared__ double qd[16][64];
  __shared__ double rz[16];
  int t = threadIdx.x;
  {
    int r = t >> 4, c = (t & 15) * 4;
    float4 qv = *(const float4*)(qf +
        ((size_t)(b * NH + h) * 64 + ig * 16 + r) * HD + c);
    qd[r][c]     = (double)qv.x; qd[r][c + 1] = (double)qv.y;
    qd[r][c + 2] = (double)qv.z; qd[r][c + 3] = (double)qv.w;
  }
  __syncthreads();
  int i = t >> 4, js = t & 15;
  const float* kbase = kf + (size_t)(b * NH + h) * NTOK * HD;
  double m = -1e300;
  for (int j = js; j < 576; j += 16) {
    const float4* k4 = (const float4*)(kbase + (size_t)j * HD);
    double acc = 0.0;
#pragma unroll
    for (int d4 = 0; d4 < 16; ++d4) {
      float4 kv = k4[d4];
      acc = fma(qd[i][d4 * 4 + 0], (double)kv.x, acc);
      acc = fma(qd[i][d4 * 4 + 1], (double)kv.y, acc);
      acc = fma(qd[i][d4 * 4 + 2], (double)kv.z, acc);
      acc = fma(qd[i][d4 * 4 + 3], (double)kv.w, acc);
    }
    double s = acc * 0.125;
    Sp[i][j] = (float)s;
    m = fmax(m, s);
  }
#pragma unroll
  for (int o = 8; o; o >>= 1) m = fmax(m, __shfl_xor(m, o));
  double z = 0.0;
  for (int j = js; j < 576; j += 16) {
    double e = exp((double)Sp[i][j] - m);
    Sp[i][j] = (float)e;
    z += e;
  }
#pragma unroll
  for (int o = 8; o; o >>= 1) z += __shfl_xor(z, o);
  if (js == 0) rz[i] = 1.0 / z;
  __syncthreads();
  // deterministic per-block column sums over the 16 rows, cols 64..575
  double* pbase = part + (((size_t)b * NH + h) * 4 + ig) * 512;
  for (int jj = t; jj < 512; jj += 256) {
    int j = 64 + jj;
    double s = 0.0;
#pragma unroll
    for (int r = 0; r < 16; ++r) s += (double)Sp[r][j] * rz[r];
    pbase[jj] = s;
  }
}

// ---------------- fixed-order fp64 reduction of the 48 partials ------------
__global__ __launch_bounds__(256)
void reduce_attnt(const double* __restrict__ part, double* __restrict__ attnt) {
  int b = blockIdx.x, t = threadIdx.x;
  for (int jj = t; jj < 512; jj += 256) {
    double acc = 0.0;
    for (int h = 0; h < NH; ++h)
#pragma unroll
      for (int ig = 0; ig < 4; ++ig)
        acc += part[(((size_t)b * NH + h) * 4 + ig) * 512 + jj];
    attnt[(size_t)b * 512 + jj] = acc * (1.0 / 768.0);
  }
}

// ---------------- fused bf16 attention (writes attn + xa) ------------------
// grid (36 q-tiles of 16, 12 heads, 32 batches)
// V is pre-transposed to (B,H,64,576): PV B-fragments straight from global.
__global__ __launch_bounds__(256)
void attn_kernel(const u16* __restrict__ qb, const u16* __restrict__ kb,
                 const u16* __restrict__ vtb, float* __restrict__ attn_out,
                 u16* __restrict__ xa) {
  int qt = blockIdx.x, h = blockIdx.y, b = blockIdx.z;
  __shared__ __align__(16) float S[16][580];
  __shared__ __align__(16) u16 qs[16][64];
  __shared__ float zrow[16];
  int t = threadIdx.x;
  int wave = t >> 6, lane = t & 63, quad = lane >> 4, l16 = lane & 15;
  size_t bh = (size_t)(b * NH + h);
  const u16* qrow = qb + (bh * NTOK + qt * 16) * HD;
  {
    int r = t >> 4, c = (t & 15) * 4;
    *(uint2*)&qs[r][c] = *(const uint2*)(qrow + (size_t)r * HD + c);
  }
  __syncthreads();
  s16x8 af0 = *(const s16x8*)&qs[l16][quad * 8];
  s16x8 af1 = *(const s16x8*)&qs[l16][32 + quad * 8];
  const u16* kbase = kb + bh * NTOK * HD;
#pragma unroll 3
  for (int jt = wave; jt < 36; jt += 4) {
    const u16* krow = kbase + (size_t)(jt * 16 + l16) * HD + quad * 8;
    s16x8 b0 = *(const s16x8*)krow;
    s16x8 b1 = *(const s16x8*)(krow + 32);
    f32x4 sacc = {0.f, 0.f, 0.f, 0.f};
    sacc = mfma16(af0, b0, sacc);
    sacc = mfma16(af1, b1, sacc);
    int col = jt * 16 + l16;
#pragma unroll
    for (int r = 0; r < 4; ++r) S[quad * 4 + r][col] = sacc[r] * 0.125f;
  }
  __syncthreads();
  // softmax over rows (16 threads per row); leave e-values in S, 1/z in zrow
  int row = t >> 4, js = t & 15;
  float m = -1e30f;
  for (int j = js; j < 576; j += 16) m = fmaxf(m, S[row][j]);
#pragma unroll
  for (int o = 8; o; o >>= 1) m = fmaxf(m, __shfl_xor(m, o));
  float z = 0.f;
  for (int j = js; j < 576; j += 16) {
    float e = expf(S[row][j] - m);
    S[row][j] = e;
    z += e;
  }
#pragma unroll
  for (int o = 8; o; o >>= 1) z += __shfl_xor(z, o);
  if (js == 0) zrow[row] = 1.0f / z;
  __syncthreads();
  // fused: normalize S in place + stream attn out (nontemporal, vec4)
  float* aout = attn_out + (bh * NTOK + qt * 16) * NTOK;
#pragma unroll
  for (int i = 0; i < 9; ++i) {
    int idx = t + i * 256;
    int r = idx / 144, c = idx - r * 144;
    float rz = zrow[r];
    f32x4 v = *(const f32x4*)&S[r][c * 4];
    v *= rz;
    *(f32x4*)&S[r][c * 4] = v;
    __builtin_nontemporal_store(v, (f32x4*)&aout[(size_t)r * NTOK + c * 4]);
  }
  __syncthreads();
  // PV: xa(16x64) = P(16x576) @ Vt(64x576)^T  -- barrier-free, pipelined
  const u16* vrow =
      vtb + (bh * HD + (size_t)(wave * 16 + l16)) * NTOK + quad * 8;
  f32x4 oacc = {0.f, 0.f, 0.f, 0.f};
#pragma unroll 6
  for (int kc = 0; kc < 18; ++kc) {
    f32x4 p0 = *(const f32x4*)&S[l16][kc * 32 + quad * 8];
    f32x4 p1 = *(const f32x4*)&S[l16][kc * 32 + quad * 8 + 4];
    union { u32 w[4]; s16x8 v; } pu;
    asm("v_cvt_pk_bf16_f32 %0, %1, %2" : "=v"(pu.w[0]) : "v"(p0[0]), "v"(p0[1]));
    asm("v_cvt_pk_bf16_f32 %0, %1, %2" : "=v"(pu.w[1]) : "v"(p0[2]), "v"(p0[3]));
    asm("v_cvt_pk_bf16_f32 %0, %1, %2" : "=v"(pu.w[2]) : "v"(p1[0]), "v"(p1[1]));
    asm("v_cvt_pk_bf16_f32 %0, %1, %2" : "=v"(pu.w[3]) : "v"(p1[2]), "v"(p1[3]));
    s16x8 bv = *(const s16x8*)(vrow + kc * 32);
    oacc = mfma16(pu.v, bv, oacc);
  }
  u16* xrow = xa + ((size_t)b * NTOK + qt * 16) * CDIM + h * HD + wave * 16 + l16;
#pragma unroll
  for (int r = 0; r < 4; ++r) xrow[(size_t)(quad * 4 + r) * CDIM] = f2bf(oacc[r]);
}

// ---------------- sort + index outputs (fp64 keys) -------------------------
__global__ __launch_bounds__(256)
void sort_select(const double* __restrict__ attnt, const int* __restrict__ gps,
                 const int* __restrict__ gs, float* dout, int* __restrict__ tops) {
  int b = blockIdx.x >> 1, grp = blockIdx.x & 1;
  __shared__ double val[256];
  __shared__ int idx[256];
  int t = threadIdx.x;
  val[t] = attnt[(size_t)b * 512 + grp * 256 + t];
  idx[t] = t;
  __syncthreads();
  for (int k = 2; k <= 256; k <<= 1) {
    for (int j = k >> 1; j > 0; j >>= 1) {
      int p = t ^ j;
      if (p > t) {
        double va = val[t], vb = val[p];
        int ia = idx[t], ib = idx[p];
        bool bfirst = (vb > va) || (vb == va && ib < ia);  // descending, stable
        bool doswap = ((t & k) == 0) ? bfirst : !bfirst;
        if (doswap) { val[t] = vb; val[p] = va; idx[t] = ib; idx[p] = ia; }
      }
      __syncthreads();
    }
  }
  const int* g = grp ? gs : gps;
  int gi = g[b * 256 + idx[t]];
  if (t < NKEEP) {
    dout[(grp ? O3 : O2) + b * NKEEP + t] = (float)gi;
    tops[b * 360 + grp * NKEEP + t] = idx[t];
  } else {
    dout[(grp ? O5 : O4) + b * NREM + (t - NKEEP)] = (float)gi;
  }
}

__global__ __launch_bounds__(256)
void idx_copy(const int* __restrict__ g, float* __restrict__ o) {
  int t = blockIdx.x * 256 + threadIdx.x;
  if (t < 2048) o[t] = (float)g[t];
}

// ---------------- gather kept tokens + LN2 ---------------------------------
__global__ __launch_bounds__(256)
void gather_ln2(const float* __restrict__ x1, const int* __restrict__ tops,
                const float* __restrict__ w, const float* __restrict__ bb,
                float* __restrict__ x2, u16* __restrict__ h2) {
  __shared__ float sc[4];
  int r = blockIdx.x, b = blockIdx.y;
  int src;
  if (r < 64)       src = r;
  else if (r < 244) src = 64 + tops[b * 360 + (r - 64)];
  else              src = 320 + tops[b * 360 + NKEEP + (r - 244)];
  const float* xr = x1 + ((size_t)b * NTOK + src) * CDIM;
  int t = threadIdx.x;
  float v0 = xr[t], v1 = xr[t + 256], v2 = xr[t + 512];
  size_t drow = ((size_t)b * NTOK2 + r) * CDIM;
  x2[drow + t] = v0; x2[drow + t + 256] = v1; x2[drow + t + 512] = v2;
  float mean = block_sum256(v0 + v1 + v2, sc) / 768.0f;
  float d0 = v0 - mean, d1 = v1 - mean, d2 = v2 - mean;
  float var = block_sum256(d0 * d0 + d1 * d1 + d2 * d2, sc) / 768.0f;
  float rs = 1.0f / sqrtf(var + 1e-5f);
  u16* hr = h2 + drow;
  hr[t]       = f2bf(d0 * rs * w[t] + bb[t]);
  hr[t + 256] = f2bf(d1 * rs * w[t + 256] + bb[t + 256]);
  hr[t + 512] = f2bf(d2 * rs * w[t + 512] + bb[t + 512]);
}

// ---------------------------------------------------------------------------
extern "C" void kernel_launch(void* const* d_in, const int* in_sizes, int n_in,
                              void* d_out, int out_size, void* d_ws,
                              size_t ws_size, hipStream_t stream) {
  const float* x     = (const float*)d_in[0];
  const int*   git   = (const int*)d_in[1];
  const int*   gps   = (const int*)d_in[2];
  const int*   gse   = (const int*)d_in[3];
  const float* ln1w  = (const float*)d_in[4];
  const float* ln1b  = (const float*)d_in[5];
  const float* qkvw  = (const float*)d_in[6];
  const float* qkvb  = (const float*)d_in[7];
  const float* projw = (const float*)d_in[8];
  const float* projb = (const float*)d_in[9];
  const float* ln2w  = (const float*)d_in[10];
  const float* ln2b  = (const float*)d_in[11];
  const float* fc1w  = (const float*)d_in[12];
  const float* fc1b  = (const float*)d_in[13];
  const float* fc2w  = (const float*)d_in[14];
  const float* fc2b  = (const float*)d_in[15];

  float* out = (float*)d_out;
  char*  ws  = (char*)d_ws;

  u16*   qkvbuf = (u16*)(ws + WS_QKV);
  u16*   mid    = (u16*)(ws + WS_QKV);   // reuse after attention
  u16*   xa     = (u16*)(ws + WS_XA);
  float* x1     = (float*)(ws + WS_X1);
  u16*   h2     = (u16*)(ws + WS_H2);
  u16*   wq     = (u16*)(ws + WS_WQ);
  u16*   wp     = (u16*)(ws + WS_WP);
  u16*   w1     = (u16*)(ws + WS_W1);
  u16*   w2     = (u16*)(ws + WS_W2);
  int*   tops   = (int*)(ws + WS_TOP);

  // fp64 sort-path scratch:
  //   partials (6 MB) live in the xa region -- dead until attn_kernel,
  //   consumed by reduce_attnt which runs before attn_kernel.
  //   attnt_d (128 KB) lives in the h2 region -- dead until gather_ln2,
  //   consumed by sort_select which runs before gather_ln2.
  double* part    = (double*)(ws + WS_XA);
  double* attnt_d = (double*)(ws + WS_H2);

  // scratch inside the attn output region (dead before attn_kernel writes it)
  float* attn6 = out + O6;
  float* hf = attn6;                       // LN1 out fp32   (14,155,776 f)
  u16*   hb = (u16*)(attn6 + 14155776);    // LN1 out bf16
  float* kf = attn6 + 21233664;            // fp32 k  (B,H,576,64)
  float* qf = attn6 + 35389440;            // fp32 q  (B,H,64,64)

  // 1. weights -> bf16
  cvt_bf16<<<1728, 256, 0, stream>>>(qkvw, wq, 442368);
  cvt_bf16<<<576, 256, 0, stream>>>(projw, wp, 147456);
  cvt_bf16<<<2304, 256, 0, stream>>>(fc1w, w1, 589824);
  cvt_bf16<<<2304, 256, 0, stream>>>(fc2w, w2, 589824);
  // 2. LN1
  ln1_kernel<<<18432, 256, 0, stream>>>(x, ln1w, ln1b, hb, hf);
  // 3. QKV GEMM (bf16); v written transposed (B,H,64,576)
  gemm_bt<2><<<dim3(36, 288), 256, 0, stream>>>(hb, wq, qkvb, nullptr, nullptr,
                                                qkvbuf, 18432, 2304, 768);
  // 4. fp32 k and q(template rows) for the sort path
  gemm_f32<0><<<dim3(12, 288), 256, 0, stream>>>(hf, qkvw + 589824, qkvb + 768,
                                                 kf, 18432, 768, 768);
  gemm_f32<1><<<dim3(12, 32), 256, 0, stream>>>(hf, qkvw, qkvb, qf, 2048, 768,
                                                768);
  // 5. precise fp64 column sums (deterministic, no atomics)
  precise_scores<<<dim3(4, 12, 32), 256, 0, stream>>>(qf, kf, part);
  reduce_attnt<<<32, 256, 0, stream>>>(part, attnt_d);
  // 6. fused attention (overwrites scratch regions with final attn / xa)
  attn_kernel<<<dim3(36, 12, 32), 256, 0, stream>>>(
      qkvbuf, qkvbuf + QKVSZ, qkvbuf + 2 * QKVSZ, attn6, xa);
  // 7. proj + residual -> x1
  gemm_bt<0><<<dim3(12, 288), 256, 0, stream>>>(xa, wp, projb, x, x1, nullptr,
                                                18432, 768, 768);
  // 8. sort / index outputs (reads attnt_d before gather_ln2 clobbers it)
  sort_select<<<64, 256, 0, stream>>>(attnt_d, gps, gse, out, tops);
  idx_copy<<<8, 256, 0, stream>>>(git, out + O1);
  // 9. gather + LN2 (x2 written straight into out0)
  gather_ln2<<<dim3(424, 32), 256, 0, stream>>>(x1, tops, ln2w, ln2b, out, h2);
  // 10. MLP
  gemm_bt<1><<<dim3(48, 212), 256, 0, stream>>>(h2, w1, fc1b, nullptr, nullptr,
                                                mid, 13568, 3072, 768);
  gemm_bt<0><<<dim3(12, 212), 256, 0, stream>>>(mid, w2, fc2b, out, out,
                                                nullptr, 13568, 768, 3072);
}